// Round 3
// baseline (306.620 us; speedup 1.0000x reference)
//
#include <hip/hip_runtime.h>
#include <hip/hip_bf16.h>

#define NEG_SLOPE 0.2f
#define BSHIFT 8                 // 256 dsts per bucket
#define BSIZE  (1 << BSHIFT)
#define CAP    9216              // pairs capacity per bucket (mean 8192, +11 sigma)
#define NBMAX  400               // max buckets (n<=102400)
#define SRC_MASK 0x1FFFF         // 17 bits for src id (n < 131072)

__device__ __forceinline__ float lrelu(float x) { return fmaxf(x, NEG_SLOPE * x); }
__device__ __forceinline__ float bf2f(unsigned short u) {
    return __uint_as_float((unsigned)u << 16);
}
__device__ __forceinline__ unsigned short f2bf(float f) {
    unsigned u = __float_as_uint(f);
    return (unsigned short)((u + 0x7fffu + ((u >> 16) & 1u)) >> 16);  // RNE
}

// Pass 1: h = A @ W as a classic LDS-tiled register GEMM.
// 64x64 tile / block (256 thr), A staged transposed (stride 68), W row-major
// (stride 68). Thread (ty,tx) computes a 4x4 register tile; per k-step:
// 2x ds_read_b128 + 16 fma, LDS offsets all compile-time immediates.
// Fused: h16 (bf16 pack) + s_i/s_j via per-thread col-partials + shfl tree.
__global__ __launch_bounds__(256) void k_gemm(
    const float* __restrict__ A, const float* __restrict__ W,
    const float* __restrict__ att,
    unsigned short* __restrict__ h16, float* __restrict__ s_i, float* __restrict__ s_j, int n)
{
    __shared__ float At[64 * 68];   // At[k*68 + r] = A[row0+r][k]
    __shared__ float Wl[64 * 68];   // Wl[k*68 + c] = W[k][c]
    const int tid  = threadIdx.x;
    const int lane = tid & 63;
    const int tx = tid & 15, ty = tid >> 4;
    const int r0 = ty * 4, c0 = tx * 4;
    const long row0 = (long)blockIdx.x * 64;

    // Stage A transposed: lane r reads its row's float4s -> conflict-free
    // LDS writes (bank = (4k + r) % 32, r spans 0..63 => 2-way max).
    {
        int r = tid & 63;
        int kb = (tid >> 6) * 4;
        long gr = row0 + r; if (gr >= n) gr = n - 1;
        const float4* Ar = (const float4*)(A + gr * 64);
#pragma unroll
        for (int p = 0; p < 4; ++p) {
            int k0 = p * 16 + kb;
            float4 a = Ar[k0 >> 2];
            At[(k0 + 0) * 68 + r] = a.x;
            At[(k0 + 1) * 68 + r] = a.y;
            At[(k0 + 2) * 68 + r] = a.z;
            At[(k0 + 3) * 68 + r] = a.w;
        }
        int c = (tid & 15) * 4;
        int rr = tid >> 4;
#pragma unroll
        for (int p = 0; p < 4; ++p) {
            int k = rr + p * 16;
            *(float4*)&Wl[k * 68 + c] = *(const float4*)(W + k * 64 + c);
        }
    }
    __syncthreads();

    float acc[4][4] = {};
#pragma unroll
    for (int k = 0; k < 64; ++k) {
        float4 a = *(const float4*)&At[k * 68 + r0];
        float4 w = *(const float4*)&Wl[k * 68 + c0];
        acc[0][0] = fmaf(a.x, w.x, acc[0][0]);
        acc[0][1] = fmaf(a.x, w.y, acc[0][1]);
        acc[0][2] = fmaf(a.x, w.z, acc[0][2]);
        acc[0][3] = fmaf(a.x, w.w, acc[0][3]);
        acc[1][0] = fmaf(a.y, w.x, acc[1][0]);
        acc[1][1] = fmaf(a.y, w.y, acc[1][1]);
        acc[1][2] = fmaf(a.y, w.z, acc[1][2]);
        acc[1][3] = fmaf(a.y, w.w, acc[1][3]);
        acc[2][0] = fmaf(a.z, w.x, acc[2][0]);
        acc[2][1] = fmaf(a.z, w.y, acc[2][1]);
        acc[2][2] = fmaf(a.z, w.z, acc[2][2]);
        acc[2][3] = fmaf(a.z, w.w, acc[2][3]);
        acc[3][0] = fmaf(a.w, w.x, acc[3][0]);
        acc[3][1] = fmaf(a.w, w.y, acc[3][1]);
        acc[3][2] = fmaf(a.w, w.z, acc[3][2]);
        acc[3][3] = fmaf(a.w, w.w, acc[3][3]);
    }

    const int rowlim = (int)(((long)n - row0) < 64 ? (n - row0) : 64);

    // h16: pack 4 bf16 -> uint2 per row, coalesced 128B per 16-lane group.
#pragma unroll
    for (int i = 0; i < 4; ++i) {
        int r = r0 + i;
        if (r < rowlim) {
            uint2 uv;
            uv.x = (unsigned)f2bf(acc[i][0]) | ((unsigned)f2bf(acc[i][1]) << 16);
            uv.y = (unsigned)f2bf(acc[i][2]) | ((unsigned)f2bf(acc[i][3]) << 16);
            *(uint2*)(h16 + (row0 + r) * 64 + c0) = uv;
        }
    }

    // s_i/s_j: col-partials then reduce over tx (lane bits 0..3).
    float4 avi = *(const float4*)(att + c0);
    float4 avj = *(const float4*)(att + 64 + c0);
#pragma unroll
    for (int i = 0; i < 4; ++i) {
        float pi = acc[i][0] * avi.x;
        pi = fmaf(acc[i][1], avi.y, pi);
        pi = fmaf(acc[i][2], avi.z, pi);
        pi = fmaf(acc[i][3], avi.w, pi);
        float pj = acc[i][0] * avj.x;
        pj = fmaf(acc[i][1], avj.y, pj);
        pj = fmaf(acc[i][2], avj.z, pj);
        pj = fmaf(acc[i][3], avj.w, pj);
#pragma unroll
        for (int o = 1; o <= 8; o <<= 1) {
            pi += __shfl_xor(pi, o, 64);
            pj += __shfl_xor(pj, o, 64);
        }
        int r = r0 + i;
        if ((lane & 15) == 0 && r < rowlim) {
            s_i[row0 + r] = pi;
            s_j[row0 + r] = pj;
        }
    }
}

// Bin step A: count per bucket in LDS, reserve global bucket space, emit packed pairs.
__global__ __launch_bounds__(256) void k_binA(
    const int* __restrict__ edges, int* __restrict__ bcursor,
    unsigned* __restrict__ pairs, int n_edges, int nb)
{
    __shared__ int hist[NBMAX];
    __shared__ int cur[NBMAX];
    int t = threadIdx.x;
    for (int b = t; b < nb; b += 256) hist[b] = 0;
    __syncthreads();
    long base = (long)blockIdx.x * 8192;

    for (int k = 0; k < 32; ++k) {
        long e = base + k * 256 + t;
        if (e < n_edges) {
            int d = edges[e];
            int i = (int)(e >> 5);
            if (d != i) atomicAdd(&hist[d >> BSHIFT], 1);
        }
    }
    __syncthreads();

    for (int b = t; b < nb; b += 256) {
        int c = hist[b];
        int g = 0;
        if (c) g = atomicAdd(&bcursor[b], c);
        cur[b] = b * CAP + g;
    }
    __syncthreads();

    for (int k = 0; k < 32; ++k) {
        long e = base + k * 256 + t;
        if (e < n_edges) {
            int d = edges[e];
            int i = (int)(e >> 5);
            if (d != i) {
                int b = d >> BSHIFT;
                int slot = atomicAdd(&cur[b], 1);
                if (slot < (b + 1) * CAP)
                    pairs[slot] = ((unsigned)(d & (BSIZE - 1)) << 17) | (unsigned)i;
            }
        }
    }
}

// Bin step B: one block per bucket. Stage pairs in LDS, per-dst hist+scan,
// scatter into a second LDS buffer (srt), then stream out fully coalesced.
// (Old version did 3.2M random 4B global writes -> ~16x write amplification.)
__global__ __launch_bounds__(512) void k_binB(
    const int* __restrict__ bcursor, unsigned* __restrict__ pairs,
    int* __restrict__ offs, int* __restrict__ counts, int n)
{
    __shared__ unsigned pl[CAP];         // 36 KB
    __shared__ unsigned srt[CAP];        // 36 KB
    __shared__ int hist[BSIZE];
    __shared__ int scn[BSIZE];
    __shared__ int cur[BSIZE];
    int b = blockIdx.x, t = threadIdx.x;
    int cnt = bcursor[b];
    if (cnt > CAP) cnt = CAP;
    long wb = (long)b * CAP;

    for (int s = t; s < cnt; s += 512) pl[s] = pairs[wb + s];
    if (t < BSIZE) hist[t] = 0;
    __syncthreads();
    for (int s = t; s < cnt; s += 512) atomicAdd(&hist[pl[s] >> 17], 1);
    __syncthreads();

    if (t < BSIZE) scn[t] = hist[t];
    __syncthreads();
    for (int d = 1; d < BSIZE; d <<= 1) {
        int v = (t >= d && t < BSIZE) ? scn[t - d] : 0;
        __syncthreads();
        if (t < BSIZE) scn[t] += v;
        __syncthreads();
    }
    if (t < BSIZE) {
        int start = scn[t] - hist[t];
        int dg = (b << BSHIFT) + t;
        if (dg < n) {
            offs[dg] = (int)(wb + start);
            counts[dg] = hist[t];
        }
        cur[t] = start;
    }
    __syncthreads();

    for (int s = t; s < cnt; s += 512) {
        unsigned pk = pl[s];
        int pos = atomicAdd(&cur[pk >> 17], 1);
        srt[pos] = pk & SRC_MASK;
    }
    __syncthreads();

    for (int s = t; s < cnt; s += 512)
        ((int*)pairs)[wb + s] = (int)srt[s];
}

// Gather: wave per dst, reshaped as 8 groups x 8 lanes.
// Each lane loads dwordx4 (8 bf16 dims) of one src row -> one wave-load
// covers 8 edges. Weights/offsets broadcast via 2 bpermutes per 8 edges.
// Invalid lanes carry w=0, so padded iterations are numerically inert
// (they read row 0 with zero weight) -- no tail code needed.
__global__ __launch_bounds__(256) void k_gather(
    const int* __restrict__ offs, const int* __restrict__ counts,
    const int* __restrict__ srcl, const unsigned short* __restrict__ h16,
    const float* __restrict__ s_i, const float* __restrict__ s_j,
    const float* __restrict__ bias, float* __restrict__ out, int n)
{
    int gw = (blockIdx.x * 256 + threadIdx.x) >> 6;
    int lane = threadIdx.x & 63;
    if (gw >= n) return;
    const int d = gw;
    const int off = offs[d], deg = counts[d];
    const float si = s_i[d];
    const float es = __expf(lrelu(si + s_j[d]));   // self-loop weight

    const int g  = lane >> 3;                      // group: which edge of 8
    const int li = lane & 7;                       // dims [li*8, li*8+8)
    const char* hb = (const char*)h16 + (li << 4); // +16B per lane-in-group

    float acc[8];
#pragma unroll
    for (int i = 0; i < 8; ++i) acc[i] = 0.f;
    float denp = 0.f;

    for (int base = 0; base < deg; base += 64) {
        int t = base + lane;
        int cnt = min(64, deg - base);
        int soff = 0; float w = 0.f;
        if (t < deg) {
            int s = srcl[off + t];
            soff = s << 7;                         // byte offset of row s
            w = __expf(lrelu(si + s_j[s]));
        }
        denp += w;
        // 16 edges per iteration: 4 bpermutes + 2 dwordx4 loads + 16 fma/lane
        for (int j = 0; j < cnt; j += 16) {
            int i0 = j + g, i1 = j + 8 + g;
            float w0 = __shfl(w, i0, 64);
            int   o0 = __shfl(soff, i0, 64);
            float w1 = __shfl(w, i1, 64);
            int   o1 = __shfl(soff, i1, 64);
            uint4 ha = *(const uint4*)(hb + o0);
            uint4 hc = *(const uint4*)(hb + o1);
            acc[0] = fmaf(__uint_as_float(ha.x << 16),          w0, acc[0]);
            acc[1] = fmaf(__uint_as_float(ha.x & 0xffff0000u),  w0, acc[1]);
            acc[2] = fmaf(__uint_as_float(ha.y << 16),          w0, acc[2]);
            acc[3] = fmaf(__uint_as_float(ha.y & 0xffff0000u),  w0, acc[3]);
            acc[4] = fmaf(__uint_as_float(ha.z << 16),          w0, acc[4]);
            acc[5] = fmaf(__uint_as_float(ha.z & 0xffff0000u),  w0, acc[5]);
            acc[6] = fmaf(__uint_as_float(ha.w << 16),          w0, acc[6]);
            acc[7] = fmaf(__uint_as_float(ha.w & 0xffff0000u),  w0, acc[7]);
            acc[0] = fmaf(__uint_as_float(hc.x << 16),          w1, acc[0]);
            acc[1] = fmaf(__uint_as_float(hc.x & 0xffff0000u),  w1, acc[1]);
            acc[2] = fmaf(__uint_as_float(hc.y << 16),          w1, acc[2]);
            acc[3] = fmaf(__uint_as_float(hc.y & 0xffff0000u),  w1, acc[3]);
            acc[4] = fmaf(__uint_as_float(hc.z << 16),          w1, acc[4]);
            acc[5] = fmaf(__uint_as_float(hc.z & 0xffff0000u),  w1, acc[5]);
            acc[6] = fmaf(__uint_as_float(hc.w << 16),          w1, acc[6]);
            acc[7] = fmaf(__uint_as_float(hc.w & 0xffff0000u),  w1, acc[7]);
        }
    }

    // reduce group partials: groups live in lane bits 3..5 -> xor 8,16,32
#pragma unroll
    for (int o = 8; o <= 32; o <<= 1) {
#pragma unroll
        for (int i = 0; i < 8; ++i)
            acc[i] += __shfl_xor(acc[i], o, 64);
    }
    // den partials over all 64 lanes
#pragma unroll
    for (int o = 32; o; o >>= 1) denp += __shfl_xor(denp, o, 64);

    // self loop + epilogue (all groups hold identical values from here on)
    uint4 hd = *(const uint4*)(hb + (d << 7));
    float den = denp + es + 1e-16f;
    float rden = 1.f / den;
    const float4* pb = (const float4*)(bias + (li << 3));
    float4 b0 = pb[0], b1 = pb[1];

    float v[8];
    v[0] = fmaf(__uint_as_float(hd.x << 16),         es, acc[0]) * rden + b0.x;
    v[1] = fmaf(__uint_as_float(hd.x & 0xffff0000u), es, acc[1]) * rden + b0.y;
    v[2] = fmaf(__uint_as_float(hd.y << 16),         es, acc[2]) * rden + b0.z;
    v[3] = fmaf(__uint_as_float(hd.y & 0xffff0000u), es, acc[3]) * rden + b0.w;
    v[4] = fmaf(__uint_as_float(hd.z << 16),         es, acc[4]) * rden + b1.x;
    v[5] = fmaf(__uint_as_float(hd.z & 0xffff0000u), es, acc[5]) * rden + b1.y;
    v[6] = fmaf(__uint_as_float(hd.w << 16),         es, acc[6]) * rden + b1.z;
    v[7] = fmaf(__uint_as_float(hd.w & 0xffff0000u), es, acc[7]) * rden + b1.w;

    float sq = 0.f;
#pragma unroll
    for (int i = 0; i < 8; ++i) sq = fmaf(v[i], v[i], sq);
#pragma unroll
    for (int o = 1; o <= 4; o <<= 1) sq += __shfl_xor(sq, o, 64);
    float rn = 1.f / fmaxf(sqrtf(sq), 1e-12f);

    if (g < 2) {   // groups 0/1 write dims [li*8+4g, li*8+4g+4) once each
        float4 ov;
        if (g == 0) ov = make_float4(v[0] * rn, v[1] * rn, v[2] * rn, v[3] * rn);
        else        ov = make_float4(v[4] * rn, v[5] * rn, v[6] * rn, v[7] * rn);
        *(float4*)(out + ((long)d << 6) + (li << 3) + (g << 2)) = ov;
    }
}

extern "C" void kernel_launch(void* const* d_in, const int* in_sizes, int n_in,
                              void* d_out, int out_size, void* d_ws, size_t ws_size,
                              hipStream_t stream)
{
    const float* A    = (const float*)d_in[0]; // all_embed (n,64) f32
    const float* W    = (const float*)d_in[1]; // (64,64) f32
    const float* att  = (const float*)d_in[2]; // (128,) f32
    const float* bias = (const float*)d_in[3]; // (64,) f32
    const int* edges  = (const int*)d_in[7];   // (n,32) int32

    int n = in_sizes[0] / 64;          // 100000
    int n_edges = in_sizes[7];         // n * 32
    int nb = (n + BSIZE - 1) >> BSHIFT; // 391 buckets

    // workspace layout
    unsigned short* h16 = (unsigned short*)d_ws;    // n*64 bf16
    float* s_i      = (float*)(h16 + (long)n * 64); // n
    float* s_j      = s_i + n;                      // n
    int* offs       = (int*)(s_j + n);              // n
    int* counts     = offs + n;                     // n
    int* bcursor    = counts + n;                   // 512
    unsigned* pairs = (unsigned*)(bcursor + 512);   // nb*CAP (aliased as srcl after binB)

    (void)hipMemsetAsync(bcursor, 0, 512 * sizeof(int), stream);

    int blocks_rows = (n + 63) / 64;                // 64 rows per block
    k_gemm<<<blocks_rows, 256, 0, stream>>>(A, W, att, h16, s_i, s_j, n);

    int blocks_binA = (n_edges + 8191) / 8192;
    k_binA<<<blocks_binA, 256, 0, stream>>>(edges, bcursor, pairs, n_edges, nb);

    k_binB<<<nb, 512, 0, stream>>>(bcursor, pairs, offs, counts, n);

    int blocks_waves = ((long)n * 64 + 255) / 256;  // wave per dst
    k_gather<<<blocks_waves, 256, 0, stream>>>(offs, counts, (const int*)pairs, h16,
                                               s_i, s_j, bias, (float*)d_out, n);
}

// Round 5
// 223.583 us; speedup vs baseline: 1.3714x; 1.3714x over previous
//
#include <hip/hip_runtime.h>
#include <hip/hip_bf16.h>

#define NEG_SLOPE 0.2f
#define BSHIFT 8                 // 256 dsts per bucket
#define BSIZE  (1 << BSHIFT)
#define CAP    9216              // pairs capacity per bucket (mean 8192, +11 sigma)
#define NBMAX  400               // max buckets (n<=102400)
#define SRC_MASK 0x1FFFF         // 17 bits for src id (n < 131072)

__device__ __forceinline__ float lrelu(float x) { return fmaxf(x, NEG_SLOPE * x); }
__device__ __forceinline__ float bf2f(unsigned short u) {
    return __uint_as_float((unsigned)u << 16);
}
__device__ __forceinline__ unsigned short f2bf(float f) {
    unsigned u = __float_as_uint(f);
    return (unsigned short)((u + 0x7fffu + ((u >> 16) & 1u)) >> 16);  // RNE
}

// Pass 1: h = A @ W as a classic LDS-tiled register GEMM.
// 64x64 tile / block (256 thr), A staged transposed (stride 68), W row-major
// (stride 68). Thread (ty,tx) computes a 4x4 register tile; per k-step:
// 2x ds_read_b128 + 16 fma, LDS offsets all compile-time immediates.
// k-loop unroll CAPPED at 4: full unroll hoisted 128 ds_reads -> 256 VGPR
// + scratch spill (WRITE_SIZE 142MB, occupancy 9.6%, 107us in round 3).
// Fused: h16 (bf16 pack) + s_i/s_j via per-thread col-partials + shfl tree.
__global__ __launch_bounds__(256, 4) void k_gemm(
    const float* __restrict__ A, const float* __restrict__ W,
    const float* __restrict__ att,
    unsigned short* __restrict__ h16, float* __restrict__ s_i, float* __restrict__ s_j, int n)
{
    __shared__ float At[64 * 68];   // At[k*68 + r] = A[row0+r][k]
    __shared__ float Wl[64 * 68];   // Wl[k*68 + c] = W[k][c]
    const int tid  = threadIdx.x;
    const int lane = tid & 63;
    const int tx = tid & 15, ty = tid >> 4;
    const int r0 = ty * 4, c0 = tx * 4;
    const long row0 = (long)blockIdx.x * 64;

    // Stage A transposed: lane r reads its row's float4s -> conflict-free
    // LDS writes (bank = (4k + r) % 32, r spans 0..63 => 2-way max).
    {
        int r = tid & 63;
        int kb = (tid >> 6) * 4;
        long gr = row0 + r; if (gr >= n) gr = n - 1;
        const float4* Ar = (const float4*)(A + gr * 64);
#pragma unroll
        for (int p = 0; p < 4; ++p) {
            int k0 = p * 16 + kb;
            float4 a = Ar[k0 >> 2];
            At[(k0 + 0) * 68 + r] = a.x;
            At[(k0 + 1) * 68 + r] = a.y;
            At[(k0 + 2) * 68 + r] = a.z;
            At[(k0 + 3) * 68 + r] = a.w;
        }
        int c = (tid & 15) * 4;
        int rr = tid >> 4;
#pragma unroll
        for (int p = 0; p < 4; ++p) {
            int k = rr + p * 16;
            *(float4*)&Wl[k * 68 + c] = *(const float4*)(W + k * 64 + c);
        }
    }
    __syncthreads();

    float acc[4][4] = {};
#pragma unroll 4
    for (int k = 0; k < 64; ++k) {
        float4 a = *(const float4*)&At[k * 68 + r0];
        float4 w = *(const float4*)&Wl[k * 68 + c0];
        acc[0][0] = fmaf(a.x, w.x, acc[0][0]);
        acc[0][1] = fmaf(a.x, w.y, acc[0][1]);
        acc[0][2] = fmaf(a.x, w.z, acc[0][2]);
        acc[0][3] = fmaf(a.x, w.w, acc[0][3]);
        acc[1][0] = fmaf(a.y, w.x, acc[1][0]);
        acc[1][1] = fmaf(a.y, w.y, acc[1][1]);
        acc[1][2] = fmaf(a.y, w.z, acc[1][2]);
        acc[1][3] = fmaf(a.y, w.w, acc[1][3]);
        acc[2][0] = fmaf(a.z, w.x, acc[2][0]);
        acc[2][1] = fmaf(a.z, w.y, acc[2][1]);
        acc[2][2] = fmaf(a.z, w.z, acc[2][2]);
        acc[2][3] = fmaf(a.z, w.w, acc[2][3]);
        acc[3][0] = fmaf(a.w, w.x, acc[3][0]);
        acc[3][1] = fmaf(a.w, w.y, acc[3][1]);
        acc[3][2] = fmaf(a.w, w.z, acc[3][2]);
        acc[3][3] = fmaf(a.w, w.w, acc[3][3]);
    }

    const int rowlim = (int)(((long)n - row0) < 64 ? (n - row0) : 64);

    // h16: pack 4 bf16 -> uint2 per row, coalesced 128B per 16-lane group.
#pragma unroll
    for (int i = 0; i < 4; ++i) {
        int r = r0 + i;
        if (r < rowlim) {
            uint2 uv;
            uv.x = (unsigned)f2bf(acc[i][0]) | ((unsigned)f2bf(acc[i][1]) << 16);
            uv.y = (unsigned)f2bf(acc[i][2]) | ((unsigned)f2bf(acc[i][3]) << 16);
            *(uint2*)(h16 + (row0 + r) * 64 + c0) = uv;
        }
    }

    // s_i/s_j: col-partials then reduce over tx (lane bits 0..3).
    float4 avi = *(const float4*)(att + c0);
    float4 avj = *(const float4*)(att + 64 + c0);
#pragma unroll
    for (int i = 0; i < 4; ++i) {
        float pi = acc[i][0] * avi.x;
        pi = fmaf(acc[i][1], avi.y, pi);
        pi = fmaf(acc[i][2], avi.z, pi);
        pi = fmaf(acc[i][3], avi.w, pi);
        float pj = acc[i][0] * avj.x;
        pj = fmaf(acc[i][1], avj.y, pj);
        pj = fmaf(acc[i][2], avj.z, pj);
        pj = fmaf(acc[i][3], avj.w, pj);
#pragma unroll
        for (int o = 1; o <= 8; o <<= 1) {
            pi += __shfl_xor(pi, o, 64);
            pj += __shfl_xor(pj, o, 64);
        }
        int r = r0 + i;
        if ((lane & 15) == 0 && r < rowlim) {
            s_i[row0 + r] = pi;
            s_j[row0 + r] = pj;
        }
    }
}

// Bin step A: count per bucket in LDS, reserve global bucket space, emit packed pairs.
__global__ __launch_bounds__(256) void k_binA(
    const int* __restrict__ edges, int* __restrict__ bcursor,
    unsigned* __restrict__ pairs, int n_edges, int nb)
{
    __shared__ int hist[NBMAX];
    __shared__ int cur[NBMAX];
    int t = threadIdx.x;
    for (int b = t; b < nb; b += 256) hist[b] = 0;
    __syncthreads();
    long base = (long)blockIdx.x * 8192;

    for (int k = 0; k < 32; ++k) {
        long e = base + k * 256 + t;
        if (e < n_edges) {
            int d = edges[e];
            int i = (int)(e >> 5);
            if (d != i) atomicAdd(&hist[d >> BSHIFT], 1);
        }
    }
    __syncthreads();

    for (int b = t; b < nb; b += 256) {
        int c = hist[b];
        int g = 0;
        if (c) g = atomicAdd(&bcursor[b], c);
        cur[b] = b * CAP + g;
    }
    __syncthreads();

    for (int k = 0; k < 32; ++k) {
        long e = base + k * 256 + t;
        if (e < n_edges) {
            int d = edges[e];
            int i = (int)(e >> 5);
            if (d != i) {
                int b = d >> BSHIFT;
                int slot = atomicAdd(&cur[b], 1);
                if (slot < (b + 1) * CAP)
                    pairs[slot] = ((unsigned)(d & (BSIZE - 1)) << 17) | (unsigned)i;
            }
        }
    }
}

// Bin step B: one block per bucket. Stage pairs in LDS, per-dst hist+scan,
// scatter into a second LDS buffer (srt), then stream out fully coalesced.
__global__ __launch_bounds__(512) void k_binB(
    const int* __restrict__ bcursor, unsigned* __restrict__ pairs,
    int* __restrict__ offs, int* __restrict__ counts, int n)
{
    __shared__ unsigned pl[CAP];         // 36 KB
    __shared__ unsigned srt[CAP];        // 36 KB
    __shared__ int hist[BSIZE];
    __shared__ int scn[BSIZE];
    __shared__ int cur[BSIZE];
    int b = blockIdx.x, t = threadIdx.x;
    int cnt = bcursor[b];
    if (cnt > CAP) cnt = CAP;
    long wb = (long)b * CAP;

    for (int s = t; s < cnt; s += 512) pl[s] = pairs[wb + s];
    if (t < BSIZE) hist[t] = 0;
    __syncthreads();
    for (int s = t; s < cnt; s += 512) atomicAdd(&hist[pl[s] >> 17], 1);
    __syncthreads();

    if (t < BSIZE) scn[t] = hist[t];
    __syncthreads();
    for (int d = 1; d < BSIZE; d <<= 1) {
        int v = (t >= d && t < BSIZE) ? scn[t - d] : 0;
        __syncthreads();
        if (t < BSIZE) scn[t] += v;
        __syncthreads();
    }
    if (t < BSIZE) {
        int start = scn[t] - hist[t];
        int dg = (b << BSHIFT) + t;
        if (dg < n) {
            offs[dg] = (int)(wb + start);
            counts[dg] = hist[t];
        }
        cur[t] = start;
    }
    __syncthreads();

    for (int s = t; s < cnt; s += 512) {
        unsigned pk = pl[s];
        int pos = atomicAdd(&cur[pk >> 17], 1);
        srt[pos] = pk & SRC_MASK;
    }
    __syncthreads();

    for (int s = t; s < cnt; s += 512)
        ((int*)pairs)[wb + s] = (int)srt[s];
}

// Gather: wave per dst, reshaped as 8 groups x 8 lanes.
// Each lane loads dwordx4 (8 bf16 dims) of one src row -> one wave-load
// covers 8 edges. Weights/offsets broadcast via 2 bpermutes per 8 edges.
// Invalid lanes carry w=0, so padded iterations are numerically inert
// (they read row 0 with zero weight) -- no tail code needed.
__global__ __launch_bounds__(256) void k_gather(
    const int* __restrict__ offs, const int* __restrict__ counts,
    const int* __restrict__ srcl, const unsigned short* __restrict__ h16,
    const float* __restrict__ s_i, const float* __restrict__ s_j,
    const float* __restrict__ bias, float* __restrict__ out, int n)
{
    int gw = (blockIdx.x * 256 + threadIdx.x) >> 6;
    int lane = threadIdx.x & 63;
    if (gw >= n) return;
    const int d = gw;
    const int off = offs[d], deg = counts[d];
    const float si = s_i[d];
    const float es = __expf(lrelu(si + s_j[d]));   // self-loop weight

    const int g  = lane >> 3;                      // group: which edge of 8
    const int li = lane & 7;                       // dims [li*8, li*8+8)
    const char* hb = (const char*)h16 + (li << 4); // +16B per lane-in-group

    float acc[8];
#pragma unroll
    for (int i = 0; i < 8; ++i) acc[i] = 0.f;
    float denp = 0.f;

    for (int base = 0; base < deg; base += 64) {
        int t = base + lane;
        int cnt = min(64, deg - base);
        int soff = 0; float w = 0.f;
        if (t < deg) {
            int s = srcl[off + t];
            soff = s << 7;                         // byte offset of row s
            w = __expf(lrelu(si + s_j[s]));
        }
        denp += w;
        // 16 edges per iteration: 4 bpermutes + 2 dwordx4 loads + 16 fma/lane
        for (int j = 0; j < cnt; j += 16) {
            int i0 = j + g, i1 = j + 8 + g;
            float w0 = __shfl(w, i0, 64);
            int   o0 = __shfl(soff, i0, 64);
            float w1 = __shfl(w, i1, 64);
            int   o1 = __shfl(soff, i1, 64);
            uint4 ha = *(const uint4*)(hb + o0);
            uint4 hc = *(const uint4*)(hb + o1);
            acc[0] = fmaf(__uint_as_float(ha.x << 16),          w0, acc[0]);
            acc[1] = fmaf(__uint_as_float(ha.x & 0xffff0000u),  w0, acc[1]);
            acc[2] = fmaf(__uint_as_float(ha.y << 16),          w0, acc[2]);
            acc[3] = fmaf(__uint_as_float(ha.y & 0xffff0000u),  w0, acc[3]);
            acc[4] = fmaf(__uint_as_float(ha.z << 16),          w0, acc[4]);
            acc[5] = fmaf(__uint_as_float(ha.z & 0xffff0000u),  w0, acc[5]);
            acc[6] = fmaf(__uint_as_float(ha.w << 16),          w0, acc[6]);
            acc[7] = fmaf(__uint_as_float(ha.w & 0xffff0000u),  w0, acc[7]);
            acc[0] = fmaf(__uint_as_float(hc.x << 16),          w1, acc[0]);
            acc[1] = fmaf(__uint_as_float(hc.x & 0xffff0000u),  w1, acc[1]);
            acc[2] = fmaf(__uint_as_float(hc.y << 16),          w1, acc[2]);
            acc[3] = fmaf(__uint_as_float(hc.y & 0xffff0000u),  w1, acc[3]);
            acc[4] = fmaf(__uint_as_float(hc.z << 16),          w1, acc[4]);
            acc[5] = fmaf(__uint_as_float(hc.z & 0xffff0000u),  w1, acc[5]);
            acc[6] = fmaf(__uint_as_float(hc.w << 16),          w1, acc[6]);
            acc[7] = fmaf(__uint_as_float(hc.w & 0xffff0000u),  w1, acc[7]);
        }
    }

    // reduce group partials: groups live in lane bits 3..5 -> xor 8,16,32
#pragma unroll
    for (int o = 8; o <= 32; o <<= 1) {
#pragma unroll
        for (int i = 0; i < 8; ++i)
            acc[i] += __shfl_xor(acc[i], o, 64);
    }
    // den partials over all 64 lanes
#pragma unroll
    for (int o = 32; o; o >>= 1) denp += __shfl_xor(denp, o, 64);

    // self loop + epilogue (all groups hold identical values from here on)
    uint4 hd = *(const uint4*)(hb + (d << 7));
    float den = denp + es + 1e-16f;
    float rden = 1.f / den;
    const float4* pb = (const float4*)(bias + (li << 3));
    float4 b0 = pb[0], b1 = pb[1];

    float v[8];
    v[0] = fmaf(__uint_as_float(hd.x << 16),         es, acc[0]) * rden + b0.x;
    v[1] = fmaf(__uint_as_float(hd.x & 0xffff0000u), es, acc[1]) * rden + b0.y;
    v[2] = fmaf(__uint_as_float(hd.y << 16),         es, acc[2]) * rden + b0.z;
    v[3] = fmaf(__uint_as_float(hd.y & 0xffff0000u), es, acc[3]) * rden + b0.w;
    v[4] = fmaf(__uint_as_float(hd.z << 16),         es, acc[4]) * rden + b1.x;
    v[5] = fmaf(__uint_as_float(hd.z & 0xffff0000u), es, acc[5]) * rden + b1.y;
    v[6] = fmaf(__uint_as_float(hd.w << 16),         es, acc[6]) * rden + b1.z;
    v[7] = fmaf(__uint_as_float(hd.w & 0xffff0000u), es, acc[7]) * rden + b1.w;

    float sq = 0.f;
#pragma unroll
    for (int i = 0; i < 8; ++i) sq = fmaf(v[i], v[i], sq);
#pragma unroll
    for (int o = 1; o <= 4; o <<= 1) sq += __shfl_xor(sq, o, 64);
    float rn = 1.f / fmaxf(sqrtf(sq), 1e-12f);

    if (g < 2) {   // groups 0/1 write dims [li*8+4g, li*8+4g+4) once each
        float4 ov;
        if (g == 0) ov = make_float4(v[0] * rn, v[1] * rn, v[2] * rn, v[3] * rn);
        else        ov = make_float4(v[4] * rn, v[5] * rn, v[6] * rn, v[7] * rn);
        *(float4*)(out + ((long)d << 6) + (li << 3) + (g << 2)) = ov;
    }
}

extern "C" void kernel_launch(void* const* d_in, const int* in_sizes, int n_in,
                              void* d_out, int out_size, void* d_ws, size_t ws_size,
                              hipStream_t stream)
{
    const float* A    = (const float*)d_in[0]; // all_embed (n,64) f32
    const float* W    = (const float*)d_in[1]; // (64,64) f32
    const float* att  = (const float*)d_in[2]; // (128,) f32
    const float* bias = (const float*)d_in[3]; // (64,) f32
    const int* edges  = (const int*)d_in[7];   // (n,32) int32

    int n = in_sizes[0] / 64;          // 100000
    int n_edges = in_sizes[7];         // n * 32
    int nb = (n + BSIZE - 1) >> BSHIFT; // 391 buckets

    // workspace layout
    unsigned short* h16 = (unsigned short*)d_ws;    // n*64 bf16
    float* s_i      = (float*)(h16 + (long)n * 64); // n
    float* s_j      = s_i + n;                      // n
    int* offs       = (int*)(s_j + n);              // n
    int* counts     = offs + n;                     // n
    int* bcursor    = counts + n;                   // 512
    unsigned* pairs = (unsigned*)(bcursor + 512);   // nb*CAP (aliased as srcl after binB)

    (void)hipMemsetAsync(bcursor, 0, 512 * sizeof(int), stream);

    int blocks_rows = (n + 63) / 64;                // 64 rows per block
    k_gemm<<<blocks_rows, 256, 0, stream>>>(A, W, att, h16, s_i, s_j, n);

    int blocks_binA = (n_edges + 8191) / 8192;
    k_binA<<<blocks_binA, 256, 0, stream>>>(edges, bcursor, pairs, n_edges, nb);

    k_binB<<<nb, 512, 0, stream>>>(bcursor, pairs, offs, counts, n);

    int blocks_waves = ((long)n * 64 + 255) / 256;  // wave per dst
    k_gather<<<blocks_waves, 256, 0, stream>>>(offs, counts, (const int*)pairs, h16,
                                               s_i, s_j, bias, (float*)d_out, n);
}